// Round 11
// baseline (161.319 us; speedup 1.0000x reference)
//
#include <hip/hip_runtime.h>
#include <math.h>

#define HID 2048
#define MAXLEN 128
#define VOCAB 32000

typedef float f4 __attribute__((ext_vector_type(4)));

__device__ __forceinline__ float wave_sum(float v) {
    #pragma unroll
    for (int m = 1; m < 64; m <<= 1) v += __shfl_xor(v, m, 64);
    return v;
}

__device__ __forceinline__ float dot4(float4 a, float4 b) {
    return a.x * b.x + a.y * b.y + a.z * b.z + a.w * b.w;
}
__device__ __forceinline__ float dot4v(f4 a, f4 b) {
    return a.x * b.x + a.y * b.y + a.z * b.z + a.w * b.w;
}

// block-level reduce for 256 threads (4 waves); same value on all threads
__device__ __forceinline__ float block_sum256(float v) {
    __shared__ float s[4];
    v = wave_sum(v);
    const int lane = threadIdx.x & 63, w = threadIdx.x >> 6;
    if (lane == 0) s[w] = v;
    __syncthreads();
    return s[0] + s[1] + s[2] + s[3];
}

// 2048-wide dot of row `w` against vector `x` (both float4*), 256 threads
__device__ __forceinline__ float row_dot2048(const float4* __restrict__ w,
                                             const float4* __restrict__ x) {
    const int t = threadIdx.x;
    return dot4(w[t], x[t]) + dot4(w[t + 256], x[t + 256]);
}

// ---- K1: blocks [0,2048) H1 rows; [2048,2176) ALe rows; [2176,4224) Oe rows ----
__global__ __launch_bounds__(256)
void k1_fused_left(const float* __restrict__ W_ih, const float* __restrict__ W_hh,
                   const float* __restrict__ emb, const int* __restrict__ tok,
                   const float* __restrict__ hidden,
                   const float* __restrict__ b_ih, const float* __restrict__ b_hh,
                   const float* __restrict__ attn_W, const float* __restrict__ attn_b,
                   const float* __restrict__ comb_W, const float* __restrict__ comb_b,
                   float* __restrict__ H1, float* __restrict__ ALe,
                   float* __restrict__ Oe) {
    const float4* xemb = (const float4*)(emb + (size_t)tok[0] * HID);
    const int bid = blockIdx.x, t = threadIdx.x;
    if (bid < HID) {                       // H1 row
        const float4* w1 = (const float4*)(W_ih + (size_t)bid * HID);
        const float4* w2 = (const float4*)(W_hh + (size_t)bid * HID);
        float p = row_dot2048(w1, xemb) + row_dot2048(w2, (const float4*)hidden);
        p = block_sum256(p);
        if (t == 0) H1[bid] = tanhf(p + b_ih[bid] + b_hh[bid]);
    } else if (bid < HID + MAXLEN) {       // attn-left row
        const int l = bid - HID;
        const float4* w = (const float4*)(attn_W + (size_t)l * 2 * HID);
        float p = block_sum256(row_dot2048(w, xemb));
        if (t == 0) ALe[l] = p + attn_b[l];
    } else {                               // comb-left row
        const int r = bid - HID - MAXLEN;
        const float4* w = (const float4*)(comb_W + (size_t)r * 2 * HID);
        float p = block_sum256(row_dot2048(w, xemb));
        if (t == 0) Oe[r] = p + comb_b[r];
    }
}

// ---- K23: fused attn-right + softmax + apply. 32 blocks; each block redundantly
// computes all 128 attn logits (attn_W_right L3-hot: 1 MB/block, 32 MB aggregate
// from L2/L3 ~ 1 µs), then its 64-col slice of AA = softmax·enc.
// Deterministic: same reduction order in every block. REGULAR loads only. ----
__global__ __launch_bounds__(256)
void k23_attn_softmax_apply(const float* __restrict__ attn_W,
                            const float* __restrict__ H1, const float* __restrict__ ALe,
                            const float* __restrict__ enc, float* __restrict__ AA) {
    __shared__ float sAL[MAXLEN];
    __shared__ float wts[MAXLEN];
    __shared__ float cs[4][64];
    const int t = threadIdx.x, lane = t & 63, wid = t >> 6;
    const float4* h1 = (const float4*)H1;
    // phase 1: wave w computes logits [32w, 32w+32)
    for (int li = 0; li < 32; ++li) {
        const int l = wid * 32 + li;
        const float4* w = (const float4*)(attn_W + (size_t)l * 2 * HID + HID);
        float p = 0.f;
        #pragma unroll
        for (int k = 0; k < 8; ++k) p += dot4(w[lane + k * 64], h1[lane + k * 64]);
        p = wave_sum(p);
        if (lane == 0) sAL[l] = ALe[l] + p;
    }
    __syncthreads();
    // phase 2: redundant per-thread softmax stats (deterministic)
    float m = sAL[0];
    for (int l = 1; l < MAXLEN; ++l) m = fmaxf(m, sAL[l]);
    float s = 0.f;
    for (int l = 0; l < MAXLEN; ++l) s += expf(sAL[l] - m);
    if (t < MAXLEN) wts[t] = expf(sAL[t] - m) / s;
    __syncthreads();
    // phase 3: apply to enc, 64 cols per block, L-split across waves
    const int j = blockIdx.x * 64 + lane;
    float acc = 0.f;
    #pragma unroll 8
    for (int l = wid; l < MAXLEN; l += 4) acc += wts[l] * enc[(size_t)l * HID + j];
    cs[wid][lane] = acc;
    __syncthreads();
    if (t < 64) AA[blockIdx.x * 64 + t] = cs[0][t] + cs[1][t] + cs[2][t] + cs[3][t];
}

// ---- K4: O = relu(Oe + comb_W_right·AA) ----
__global__ __launch_bounds__(256)
void k4_comb_right(const float* __restrict__ comb_W, const float* __restrict__ AA,
                   const float* __restrict__ Oe, float* __restrict__ O) {
    const int r = blockIdx.x, t = threadIdx.x;
    const float4* w = (const float4*)(comb_W + (size_t)r * 2 * HID + HID);
    float p = block_sum256(row_dot2048(w, (const float4*)AA));
    if (t == 0) O[r] = fmaxf(Oe[r] + p, 0.f);
}

// ---- K5: OH = tanh(W_ih·O + W_hh·H1 + b_ih + b_hh) (weights L3-warm from K1) ----
__global__ __launch_bounds__(256)
void k5_rnn2(const float* __restrict__ W_ih, const float* __restrict__ W_hh,
             const float* __restrict__ O, const float* __restrict__ H1,
             const float* __restrict__ b_ih, const float* __restrict__ b_hh,
             float* __restrict__ OH) {
    const int r = blockIdx.x, t = threadIdx.x;
    const float4* w1 = (const float4*)(W_ih + (size_t)r * HID);
    const float4* w2 = (const float4*)(W_hh + (size_t)r * HID);
    float p = row_dot2048(w1, (const float4*)O) + row_dot2048(w2, (const float4*)H1);
    p = block_sum256(p);
    if (t == 0) OH[r] = tanhf(p + b_ih[r] + b_hh[r]);
}

// ---- K6: big matvec, 4 rows/wave, regular loads, unroll 4 (16 loads in flight) ----
// |logit| <= ||W row||·||OH|| ~ 41 -> exp() without max-subtraction is f32-safe.
__global__ __launch_bounds__(256)
void k6_bigmv(const float* __restrict__ W, const float* __restrict__ x,
              const float* __restrict__ b, float* __restrict__ out,
              float* __restrict__ PE) {
    __shared__ float red[4];
    const int wid = threadIdx.x >> 6, lane = threadIdx.x & 63;
    const int r0 = blockIdx.x * 16 + wid * 4;           // rows r0..r0+3
    const f4* xv = (const f4*)x;
    const f4* w0 = (const f4*)(W + (size_t)r0 * HID);   // 512 f4 per row
    const f4* w1 = w0 + 512;
    const f4* w2 = w0 + 1024;
    const f4* w3 = w0 + 1536;
    float a0 = 0.f, a1 = 0.f, a2 = 0.f, a3 = 0.f;
    #pragma unroll 4
    for (int k = 0; k < 8; ++k) {
        const int idx = lane + k * 64;
        const f4 xc = xv[idx];
        a0 += dot4v(w0[idx], xc);
        a1 += dot4v(w1[idx], xc);
        a2 += dot4v(w2[idx], xc);
        a3 += dot4v(w3[idx], xc);
    }
    a0 = wave_sum(a0);
    a1 = wave_sum(a1);
    a2 = wave_sum(a2);
    a3 = wave_sum(a3);
    if (lane == 0) {
        const f4 bb = *(const f4*)(b + r0);
        a0 += bb.x; a1 += bb.y; a2 += bb.z; a3 += bb.w;
        f4 o; o.x = a0; o.y = a1; o.z = a2; o.w = a3;
        *(f4*)(out + r0) = o;
        red[wid] = expf(a0) + expf(a1) + expf(a2) + expf(a3);
    }
    __syncthreads();
    if (threadIdx.x == 0) PE[blockIdx.x] = red[0] + red[1] + red[2] + red[3];
}

// ---- K7: every block reduces PE identically (deterministic); out -= log(sum) ----
__global__ __launch_bounds__(256)
void k7_lse_apply(const float* __restrict__ PE, float* __restrict__ out) {
    const int t = threadIdx.x;
    float s = 0.f;
    for (int i = t; i < VOCAB / 16; i += 256) s += PE[i];   // 2000 partials
    const float lg = logf(block_sum256(s));
    out[blockIdx.x * 256 + t] -= lg;                        // 125 * 256 == 32000
}

extern "C" void kernel_launch(void* const* d_in, const int* in_sizes, int n_in,
                              void* d_out, int out_size, void* d_ws, size_t ws_size,
                              hipStream_t stream) {
    const int*   tok    = (const int*)  d_in[0];
    const float* hidden = (const float*)d_in[1];
    const float* enc    = (const float*)d_in[2];
    const float* emb    = (const float*)d_in[3];
    const float* attn_W = (const float*)d_in[4];
    const float* attn_b = (const float*)d_in[5];
    const float* comb_W = (const float*)d_in[6];
    const float* comb_b = (const float*)d_in[7];
    const float* W_ih   = (const float*)d_in[8];
    const float* W_hh   = (const float*)d_in[9];
    const float* b_ih   = (const float*)d_in[10];
    const float* b_hh   = (const float*)d_in[11];
    const float* out_W  = (const float*)d_in[12];
    const float* out_b  = (const float*)d_in[13];
    float* out = (float*)d_out;

    float* ws  = (float*)d_ws;
    float* H1  = ws;          // [2048]
    float* ALe = ws + 2048;   // [128]
    float* AA  = ws + 2304;   // [2048]
    float* Oe  = ws + 4352;   // [2048]
    float* O   = ws + 6400;   // [2048]
    float* OH  = ws + 8448;   // [2048]
    float* PE  = ws + 10496;  // [2000]

    // K1: H1 + ALe + Oe   (52.4 MB, machine-filling)
    k1_fused_left<<<HID + MAXLEN + HID, 256, 0, stream>>>(W_ih, W_hh, emb, tok, hidden,
                                                          b_ih, b_hh, attn_W, attn_b,
                                                          comb_W, comb_b, H1, ALe, Oe);
    // K23: AA = softmax(ALe + attn_right·H1)·enc   (L3-hot, 32 blocks)
    k23_attn_softmax_apply<<<HID / 64, 256, 0, stream>>>(attn_W, H1, ALe, enc, AA);
    // K4: O = relu(Oe + comb_right·AA)  (16.8 MB)
    k4_comb_right<<<HID, 256, 0, stream>>>(comb_W, AA, Oe, O);
    // K5: OH = tanh(W_ih·O + W_hh·H1 + b)  (33.6 MB, L3-warm)
    k5_rnn2<<<HID, 256, 0, stream>>>(W_ih, W_hh, O, H1, b_ih, b_hh, OH);
    // K6: logits + per-block exp partials  (262 MB, 4 rows/wave)
    k6_bigmv<<<VOCAB / 16, 256, 0, stream>>>(out_W, OH, out_b, out, PE);
    // K7: out -= log(sum(exp))
    k7_lse_apply<<<VOCAB / 256, 256, 0, stream>>>(PE, out);
}

// Round 12
// 86.094 us; speedup vs baseline: 1.8737x; 1.8737x over previous
//
#include <hip/hip_runtime.h>
#include <math.h>

#define HID 2048
#define MAXLEN 128
#define VOCAB 32000

typedef float f4 __attribute__((ext_vector_type(4)));

__device__ __forceinline__ float wave_sum(float v) {
    #pragma unroll
    for (int m = 1; m < 64; m <<= 1) v += __shfl_xor(v, m, 64);
    return v;
}

__device__ __forceinline__ float dot4(float4 a, float4 b) {
    return a.x * b.x + a.y * b.y + a.z * b.z + a.w * b.w;
}
__device__ __forceinline__ float dot4v(f4 a, f4 b) {
    return a.x * b.x + a.y * b.y + a.z * b.z + a.w * b.w;
}

// block-level reduce for 256 threads (4 waves); same value on all threads
__device__ __forceinline__ float block_sum256(float v) {
    __shared__ float s[4];
    v = wave_sum(v);
    const int lane = threadIdx.x & 63, w = threadIdx.x >> 6;
    if (lane == 0) s[w] = v;
    __syncthreads();
    return s[0] + s[1] + s[2] + s[3];
}

// 2048-wide dot of row `w` against vector `x` (both float4*), 256 threads
__device__ __forceinline__ float row_dot2048(const float4* __restrict__ w,
                                             const float4* __restrict__ x) {
    const int t = threadIdx.x;
    return dot4(w[t], x[t]) + dot4(w[t + 256], x[t + 256]);
}

// ---- K1: blocks [0,2048) H1 rows; [2048,2176) ALe rows; [2176,4224) Oe rows ----
__global__ __launch_bounds__(256)
void k1_fused_left(const float* __restrict__ W_ih, const float* __restrict__ W_hh,
                   const float* __restrict__ emb, const int* __restrict__ tok,
                   const float* __restrict__ hidden,
                   const float* __restrict__ b_ih, const float* __restrict__ b_hh,
                   const float* __restrict__ attn_W, const float* __restrict__ attn_b,
                   const float* __restrict__ comb_W, const float* __restrict__ comb_b,
                   float* __restrict__ H1, float* __restrict__ ALe,
                   float* __restrict__ Oe) {
    const float4* xemb = (const float4*)(emb + (size_t)tok[0] * HID);
    const int bid = blockIdx.x, t = threadIdx.x;
    if (bid < HID) {                       // H1 row
        const float4* w1 = (const float4*)(W_ih + (size_t)bid * HID);
        const float4* w2 = (const float4*)(W_hh + (size_t)bid * HID);
        float p = row_dot2048(w1, xemb) + row_dot2048(w2, (const float4*)hidden);
        p = block_sum256(p);
        if (t == 0) H1[bid] = tanhf(p + b_ih[bid] + b_hh[bid]);
    } else if (bid < HID + MAXLEN) {       // attn-left row
        const int l = bid - HID;
        const float4* w = (const float4*)(attn_W + (size_t)l * 2 * HID);
        float p = block_sum256(row_dot2048(w, xemb));
        if (t == 0) ALe[l] = p + attn_b[l];
    } else {                               // comb-left row
        const int r = bid - HID - MAXLEN;
        const float4* w = (const float4*)(comb_W + (size_t)r * 2 * HID);
        float p = block_sum256(row_dot2048(w, xemb));
        if (t == 0) Oe[r] = p + comb_b[r];
    }
}

// ---- K2b: blocks [0,128): AL[l] = ALe[l] + attn_W_right[l]·H1
//           blocks [128,2176): OHh[r] = W_hh[r]·H1   (K5's independent half) ----
__global__ __launch_bounds__(256)
void k2b_attn_right_hh(const float* __restrict__ attn_W, const float* __restrict__ W_hh,
                       const float* __restrict__ H1, const float* __restrict__ ALe,
                       float* __restrict__ AL, float* __restrict__ OHh) {
    const int bid = blockIdx.x, t = threadIdx.x;
    const float4* h1 = (const float4*)H1;
    if (bid < MAXLEN) {
        const float4* w = (const float4*)(attn_W + (size_t)bid * 2 * HID + HID);
        float p = block_sum256(row_dot2048(w, h1));
        if (t == 0) AL[bid] = ALe[bid] + p;
    } else {
        const int r = bid - MAXLEN;
        const float4* w = (const float4*)(W_hh + (size_t)r * HID);
        float p = block_sum256(row_dot2048(w, h1));
        if (t == 0) OHh[r] = p;
    }
}

// ---- K3: AA = softmax(AL)·enc, 32 blocks x 64 cols ----
__global__ __launch_bounds__(256)
void k3_softmax_apply(const float* __restrict__ AL, const float* __restrict__ enc,
                      float* __restrict__ AA) {
    __shared__ float sAL[MAXLEN];
    __shared__ float wts[MAXLEN];
    __shared__ float cs[4][64];
    const int t = threadIdx.x;
    if (t < MAXLEN) sAL[t] = AL[t];
    __syncthreads();
    float m = sAL[0];
    for (int l = 1; l < MAXLEN; ++l) m = fmaxf(m, sAL[l]);
    float s = 0.f;
    for (int l = 0; l < MAXLEN; ++l) s += expf(sAL[l] - m);
    if (t < MAXLEN) wts[t] = expf(sAL[t] - m) / s;
    __syncthreads();
    const int j  = blockIdx.x * 64 + (t & 63);
    const int l0 = t >> 6;
    float acc = 0.f;
    #pragma unroll 8
    for (int l = l0; l < MAXLEN; l += 4) acc += wts[l] * enc[(size_t)l * HID + j];
    cs[l0][t & 63] = acc;
    __syncthreads();
    if (t < 64) AA[blockIdx.x * 64 + t] = cs[0][t] + cs[1][t] + cs[2][t] + cs[3][t];
}

// ---- K4: O = relu(Oe + comb_W_right·AA) ----
__global__ __launch_bounds__(256)
void k4_comb_right(const float* __restrict__ comb_W, const float* __restrict__ AA,
                   const float* __restrict__ Oe, float* __restrict__ O) {
    const int r = blockIdx.x, t = threadIdx.x;
    const float4* w = (const float4*)(comb_W + (size_t)r * 2 * HID + HID);
    float p = block_sum256(row_dot2048(w, (const float4*)AA));
    if (t == 0) O[r] = fmaxf(Oe[r] + p, 0.f);
}

// ---- K5: OH = tanh(W_ih·O + OHh + b_ih + b_hh)  (only 16.8 MB now) ----
__global__ __launch_bounds__(256)
void k5_rnn2(const float* __restrict__ W_ih, const float* __restrict__ O,
             const float* __restrict__ OHh,
             const float* __restrict__ b_ih, const float* __restrict__ b_hh,
             float* __restrict__ OH) {
    const int r = blockIdx.x, t = threadIdx.x;
    const float4* w1 = (const float4*)(W_ih + (size_t)r * HID);
    float p = block_sum256(row_dot2048(w1, (const float4*)O));
    if (t == 0) OH[r] = tanhf(p + OHh[r] + b_ih[r] + b_hh[r]);
}

// ---- K6: big matvec, 4 rows/wave, regular loads, unroll 4 (16 loads in flight) ----
// |logit| <= ||W row||·||OH|| ~ 41 -> exp() without max-subtraction is f32-safe.
__global__ __launch_bounds__(256)
void k6_bigmv(const float* __restrict__ W, const float* __restrict__ x,
              const float* __restrict__ b, float* __restrict__ out,
              float* __restrict__ PE) {
    __shared__ float red[4];
    const int wid = threadIdx.x >> 6, lane = threadIdx.x & 63;
    const int r0 = blockIdx.x * 16 + wid * 4;           // rows r0..r0+3
    const f4* xv = (const f4*)x;
    const f4* w0 = (const f4*)(W + (size_t)r0 * HID);   // 512 f4 per row
    const f4* w1 = w0 + 512;
    const f4* w2 = w0 + 1024;
    const f4* w3 = w0 + 1536;
    float a0 = 0.f, a1 = 0.f, a2 = 0.f, a3 = 0.f;
    #pragma unroll 4
    for (int k = 0; k < 8; ++k) {
        const int idx = lane + k * 64;
        const f4 xc = xv[idx];
        a0 += dot4v(w0[idx], xc);
        a1 += dot4v(w1[idx], xc);
        a2 += dot4v(w2[idx], xc);
        a3 += dot4v(w3[idx], xc);
    }
    a0 = wave_sum(a0);
    a1 = wave_sum(a1);
    a2 = wave_sum(a2);
    a3 = wave_sum(a3);
    if (lane == 0) {
        const f4 bb = *(const f4*)(b + r0);
        a0 += bb.x; a1 += bb.y; a2 += bb.z; a3 += bb.w;
        f4 o; o.x = a0; o.y = a1; o.z = a2; o.w = a3;
        *(f4*)(out + r0) = o;
        red[wid] = expf(a0) + expf(a1) + expf(a2) + expf(a3);
    }
    __syncthreads();
    if (threadIdx.x == 0) PE[blockIdx.x] = red[0] + red[1] + red[2] + red[3];
}

// ---- K7: every block reduces PE identically (deterministic); out -= log(sum) ----
__global__ __launch_bounds__(256)
void k7_lse_apply(const float* __restrict__ PE, float* __restrict__ out) {
    const int t = threadIdx.x;
    float s = 0.f;
    for (int i = t; i < VOCAB / 16; i += 256) s += PE[i];   // 2000 partials
    const float lg = logf(block_sum256(s));
    out[blockIdx.x * 256 + t] -= lg;                        // 125 * 256 == 32000
}

extern "C" void kernel_launch(void* const* d_in, const int* in_sizes, int n_in,
                              void* d_out, int out_size, void* d_ws, size_t ws_size,
                              hipStream_t stream) {
    const int*   tok    = (const int*)  d_in[0];
    const float* hidden = (const float*)d_in[1];
    const float* enc    = (const float*)d_in[2];
    const float* emb    = (const float*)d_in[3];
    const float* attn_W = (const float*)d_in[4];
    const float* attn_b = (const float*)d_in[5];
    const float* comb_W = (const float*)d_in[6];
    const float* comb_b = (const float*)d_in[7];
    const float* W_ih   = (const float*)d_in[8];
    const float* W_hh   = (const float*)d_in[9];
    const float* b_ih   = (const float*)d_in[10];
    const float* b_hh   = (const float*)d_in[11];
    const float* out_W  = (const float*)d_in[12];
    const float* out_b  = (const float*)d_in[13];
    float* out = (float*)d_out;

    float* ws  = (float*)d_ws;
    float* H1  = ws;          // [2048]
    float* ALe = ws + 2048;   // [128]
    float* AL  = ws + 2176;   // [128]
    float* AA  = ws + 2304;   // [2048]
    float* Oe  = ws + 4352;   // [2048]
    float* O   = ws + 6400;   // [2048]
    float* OH  = ws + 8448;   // [2048]
    float* OHh = ws + 10496;  // [2048]
    float* PE  = ws + 12544;  // [2000]

    // K1: H1 + ALe + Oe   (52.4 MB, machine-filling)
    k1_fused_left<<<HID + MAXLEN + HID, 256, 0, stream>>>(W_ih, W_hh, emb, tok, hidden,
                                                          b_ih, b_hh, attn_W, attn_b,
                                                          comb_W, comb_b, H1, ALe, Oe);
    // K2b: AL + OHh = W_hh·H1   (17.8 MB, machine-filling)
    k2b_attn_right_hh<<<MAXLEN + HID, 256, 0, stream>>>(attn_W, W_hh, H1, ALe, AL, OHh);
    // K3: AA = softmax(AL)·enc   (1 MB)
    k3_softmax_apply<<<HID / 64, 256, 0, stream>>>(AL, enc, AA);
    // K4: O = relu(Oe + comb_right·AA)  (16.8 MB)
    k4_comb_right<<<HID, 256, 0, stream>>>(comb_W, AA, Oe, O);
    // K5: OH = tanh(W_ih·O + OHh + b)  (16.8 MB)
    k5_rnn2<<<HID, 256, 0, stream>>>(W_ih, O, OHh, b_ih, b_hh, OH);
    // K6: logits + per-block exp partials  (262 MB, 4 rows/wave)
    k6_bigmv<<<VOCAB / 16, 256, 0, stream>>>(out_W, OH, out_b, out, PE);
    // K7: out -= log(sum(exp))
    k7_lse_apply<<<VOCAB / 256, 256, 0, stream>>>(PE, out);
}